// Round 22
// baseline (139.308 us; speedup 1.0000x reference)
//
#include <hip/hip_runtime.h>
#include <hip/hip_bf16.h>

#define N_NODES 50000
#define P_PATHS 200000
#define N_ROWS  250000
#define L_EDGES 6
#define T_LEN   128
#define F_BINS  65
#define EPSF    1e-12f
#define PIF     3.14159265358979323846f
#define COORD_ELEMS ((size_t)2 * (P_PATHS + N_NODES))   // 500000 f32
#define FREQ_BYTES  ((size_t)N_NODES * F_BINS * 8)      // 26 MB mark
#define ATILE_OFF   ((size_t)32 * 1024 * 1024)          // A-tile at +32 MB (64 MB)
#define XTAB_OFF    ((size_t)96 * 1024 * 1024)          // x samples at +96 MB (12.8 MB)
#define KDIM  128
#define KPADN 128
#define ROWS_BLK 64
#define TILES ((N_ROWS + ROWS_BLK - 1) / ROWS_BLK)      // 3907
#define GEMM_GRID 1024
#define STILES ((N_NODES + ROWS_BLK - 1) / ROWS_BLK)    // 782
#define SPEC_GRID 391

typedef _Float16 v2h __attribute__((ext_vector_type(2)));
typedef _Float16 v8h __attribute__((ext_vector_type(8)));
typedef float    v4f __attribute__((ext_vector_type(4)));

__device__ __forceinline__ float softplus_(float x) {
    const float e = __expf(-fabsf(x));
    return fmaxf(x, 0.0f) + __logf(1.0f + e);
}

__device__ __forceinline__ float lgamma_pos_(float x) {
    const float ser = 1.000000000190015f
                    + 76.18009172947146f     / (x + 1.0f)
                    - 86.50532032941677f     / (x + 2.0f)
                    + 24.01409824083091f     / (x + 3.0f)
                    - 1.231739572450155f     / (x + 4.0f)
                    + 0.1208650973866179e-2f / (x + 5.0f)
                    - 0.5395239384953e-5f    / (x + 6.0f);
    const float tmp = x + 5.5f;
    return (x + 0.5f) * __logf(tmp) - tmp + __logf(2.5066282746310005f * ser / x);
}

// ---------------- K0a: irfft weight matrix W^T[t][kk] (unchanged) ----------------
__global__ void irfa49s_wgen(_Float16* __restrict__ Wt) {
    const int idx = blockIdx.x * 256 + threadIdx.x;
    if (idx >= 128 * KDIM) return;
    const int t  = idx / KDIM;
    const int kk = idx - t * KDIM;
    int j; float cj; bool is_sin;
    if (kk == 1) { j = 64; cj = 1.0f; is_sin = false; }
    else {
        j = kk >> 1;
        cj = (j == 0) ? 1.0f : 2.0f;
        is_sin = (kk & 1);
    }
    const int m = (j * t) & 127;
    const float th = (float)m * (PIF / 64.0f);
    const float tri = is_sin ? -__sinf(th) : __cosf(th);
    Wt[idx] = (_Float16)(cj * tri * (1.0f / 128.0f));
}

// ---------------- K0b: forward-rfft weight matrix W2T[kk][t], fp16, 128x128 ----------------
// F[kk]=sum_t x[t]*W2T[kk][t]; kk=0 -> 1; kk=1 -> (-1)^t; kk=2j -> cos; kk=2j+1 -> -sin.
__global__ void irfa49v_w2gen(_Float16* __restrict__ W2t) {
    const int idx = blockIdx.x * 256 + threadIdx.x;
    if (idx >= 128 * 128) return;
    const int kk = idx >> 7;
    const int t  = idx & 127;
    int j; bool is_sin;
    if (kk == 1) { j = 64; is_sin = false; }
    else { j = kk >> 1; is_sin = (kk & 1); }
    const int m = (j * t) & 127;
    const float th = (float)m * (PIF / 64.0f);
    W2t[idx] = (_Float16)(is_sin ? -__sinf(th) : __cosf(th));
}

// ---------------- K1a: gamma IRF samples -> fp16 xtab[node][128] ----------------
__global__ __launch_bounds__(256) void irfa49v_xgen(const float* __restrict__ params,
                                                    _Float16* __restrict__ xtab) {
    const int tid  = threadIdx.x;
    const int node = blockIdx.x * 2 + (tid >> 7);
    const int t    = tid & 127;

    const float a  = softplus_(params[2 * node + 0]) + 1.0f;
    const float b  = softplus_(params[2 * node + 1]) + 0.5f;
    const float lg = lgamma_pos_(a);
    const float lb = __logf(b);
    const float rb = 1.0f / b;
    const float cst = -lg - a * lb;
    const float tc = (float)t + 0.5f;
    const float x  = __expf(fmaf(a - 1.0f, __logf(tc), fmaf(-tc, rb, cst)));
    xtab[(size_t)node * T_LEN + t] = (_Float16)x;
}

// ---------------- K1b: spectrum GEMM  F[50000][128] = xtab x W2T^T (B-in-regs) ----------------
__global__ __launch_bounds__(256, 2) void irfa49v_spec(const _Float16* __restrict__ xtab,
                                                       const _Float16* __restrict__ W2t,
                                                       _Float16* __restrict__ freqh) {
    const int tid  = threadIdx.x;
    const int wv   = tid >> 6;
    const int lane = tid & 63;
    const int tcol = lane & 15;
    const int kg   = lane >> 4;
    const int rgrp = kg * 4;

    v8h bf[4][8];
    #pragma unroll
    for (int kt = 0; kt < 4; ++kt) {
        #pragma unroll
        for (int nt = 0; nt < 8; ++nt) {
            bf[kt][nt] = *(const v8h*)&W2t[(nt * 16 + tcol) * 128 + kt * 32 + kg * 8];
        }
    }

    for (int tile = blockIdx.x; tile < STILES; tile += SPEC_GRID) {
        const int rowa = tile * ROWS_BLK + wv * 16 + tcol;
        v8h af[4];
        #pragma unroll
        for (int kt = 0; kt < 4; ++kt) {
            v8h v = (v8h){(_Float16)0.0f, (_Float16)0.0f, (_Float16)0.0f, (_Float16)0.0f,
                          (_Float16)0.0f, (_Float16)0.0f, (_Float16)0.0f, (_Float16)0.0f};
            if (rowa < N_NODES) v = *(const v8h*)&xtab[(size_t)rowa * T_LEN + kt * 32 + kg * 8];
            af[kt] = v;
        }

        v4f acc[8];
        #pragma unroll
        for (int nt = 0; nt < 8; ++nt) acc[nt] = (v4f){0.0f, 0.0f, 0.0f, 0.0f};
        #pragma unroll
        for (int kt = 0; kt < 4; ++kt) {
            #pragma unroll
            for (int nt = 0; nt < 8; ++nt) {
                acc[nt] = __builtin_amdgcn_mfma_f32_16x16x32_f16(af[kt], bf[kt][nt], acc[nt], 0, 0, 0);
            }
        }

        #pragma unroll
        for (int reg = 0; reg < 4; ++reg) {
            const int row = tile * ROWS_BLK + wv * 16 + rgrp + reg;
            if (row < N_NODES) {
                _Float16* op = freqh + (size_t)row * KPADN;
                #pragma unroll
                for (int nt = 0; nt < 8; ++nt) {
                    op[nt * 16 + tcol] = (_Float16)acc[nt][reg];
                }
            }
        }
    }
}

// ---------------- K2a: spectral product -> packed A-tile (unchanged) ----------------
__global__ __launch_bounds__(256) void irfa49t_prod(const _Float16* __restrict__ freqh,
                                                    const int* __restrict__ edges,
                                                    _Float16* __restrict__ Atile) {
    const int gt  = blockIdx.x * 256 + threadIdx.x;
    const int row = gt >> 5;
    const int tl  = gt & 31;
    _Float16* op = Atile + (size_t)row * KDIM;

    if (row < P_PATHS) {
        const int eb = row * L_EDGES;
        v2h av[L_EDGES], bv[L_EDGES];
        #pragma unroll
        for (int j = 0; j < L_EDGES; ++j) {
            const _Float16* fh = freqh + (size_t)edges[eb + j] * KPADN;
            av[j] = *(const v2h*)(fh + 2 * tl);
            bv[j] = *(const v2h*)(fh + 64 + 2 * tl);
        }
        float p1r = 1.0f, p1i = 0.0f, p2r = 1.0f, p2i = 0.0f, q = 1.0f;
        #pragma unroll
        for (int j = 0; j < L_EDGES; ++j) {
            const float ax  = (float)av[j][0];
            const float ayr = (float)av[j][1];
            const float ay  = (tl == 0) ? 0.0f : ayr;    // bin0.im slot holds f64.re
            float t1 = p1r * ax - p1i * ay;
            p1i      = p1r * ay + p1i * ax;
            p1r = t1;
            q *= ayr;
            const float bx = (float)bv[j][0], by = (float)bv[j][1];
            float t2 = p2r * bx - p2i * by;
            p2i      = p2r * by + p2i * bx;
            p2r = t2;
        }
        v2h h;
        h[0] = (_Float16)p1r;
        h[1] = (tl == 0) ? (_Float16)q : (_Float16)p1i;
        *(v2h*)(op + 2 * tl) = h;
        h[0] = (_Float16)p2r; h[1] = (_Float16)p2i;
        *(v2h*)(op + 64 + 2 * tl) = h;
    } else {
        const _Float16* fh = freqh + (size_t)(row - P_PATHS) * KPADN;
        *(v2h*)(op + 2 * tl)      = *(const v2h*)(fh + 2 * tl);
        *(v2h*)(op + 64 + 2 * tl) = *(const v2h*)(fh + 64 + 2 * tl);
    }
}

// ---------------- K2b: persistent MFMA GEMM, B-in-registers (unchanged) ----------------
__global__ __launch_bounds__(256, 2) void irfa49u_gemm(const _Float16* __restrict__ Atile,
                                                       const _Float16* __restrict__ Wt,
                                                       float* __restrict__ out_agg) {
    const int tid  = threadIdx.x;
    const int wv   = tid >> 6;
    const int lane = tid & 63;
    const int tcol = lane & 15;
    const int kg   = lane >> 4;
    const int rgrp = kg * 4;

    v8h bf[4][8];
    #pragma unroll
    for (int kt = 0; kt < 4; ++kt) {
        #pragma unroll
        for (int nt = 0; nt < 8; ++nt) {
            bf[kt][nt] = *(const v8h*)&Wt[(nt * 16 + tcol) * KDIM + kt * 32 + kg * 8];
        }
    }

    for (int tile = blockIdx.x; tile < TILES; tile += GEMM_GRID) {
        const int rowa = tile * ROWS_BLK + wv * 16 + tcol;
        const _Float16* ap = Atile + (size_t)rowa * KDIM + kg * 8;

        v8h af[4];
        #pragma unroll
        for (int kt = 0; kt < 4; ++kt) af[kt] = *(const v8h*)(ap + kt * 32);

        v4f acc[8];
        #pragma unroll
        for (int nt = 0; nt < 8; ++nt) acc[nt] = (v4f){0.0f, 0.0f, 0.0f, 0.0f};

        #pragma unroll
        for (int kt = 0; kt < 4; ++kt) {
            #pragma unroll
            for (int nt = 0; nt < 8; ++nt) {
                acc[nt] = __builtin_amdgcn_mfma_f32_16x16x32_f16(af[kt], bf[kt][nt], acc[nt], 0, 0, 0);
            }
        }

        #pragma unroll
        for (int reg = 0; reg < 4; ++reg) {
            float vals[8];
            float vsum = 0.0f;
            #pragma unroll
            for (int nt = 0; nt < 8; ++nt) {
                const float v = fmaxf(acc[nt][reg], 0.0f);
                vals[nt] = v;
                vsum += v;
            }
            vsum += __shfl_xor(vsum, 1);
            vsum += __shfl_xor(vsum, 2);
            vsum += __shfl_xor(vsum, 4);
            vsum += __shfl_xor(vsum, 8);
            const int row = tile * ROWS_BLK + wv * 16 + rgrp + reg;
            if (row < N_ROWS) {
                const float inv = 1.0f / (vsum + EPSF);
                float* op = out_agg + (size_t)row * T_LEN;
                #pragma unroll
                for (int nt = 0; nt < 8; ++nt) {
                    const int t = nt * 16 + tcol;
                    op[127 - t] = vals[nt] * inv;
                }
            }
        }
    }
}

// ---------------- K3: coords as f32 (unchanged) ----------------
__global__ void IRFAggregator_39049842655549_kernel(const int* __restrict__ edges,
                                                    float* __restrict__ out) {
    const int M = P_PATHS + N_NODES;
    const int i = blockIdx.x * blockDim.x + threadIdx.x;
    if (i >= 2 * M) return;
    int v;
    if (i < P_PATHS) {
        v = edges[i * L_EDGES];
    } else if (i < M) {
        v = i - P_PATHS;
    } else {
        const int j = i - M;
        if (j < P_PATHS) v = edges[j * L_EDGES + L_EDGES - 1];
        else             v = j - P_PATHS;
    }
    out[i] = (float)v;
}

extern "C" void kernel_launch(void* const* d_in, const int* in_sizes, int n_in,
                              void* d_out, int out_size, void* d_ws, size_t ws_size,
                              hipStream_t stream) {
    const float* params = (const float*)d_in[0];
    const int*   edges  = (const int*)d_in[1];

    _Float16* freqh = (_Float16*)d_ws;                                 // 12.8 MB
    _Float16* Wt    = (_Float16*)((char*)d_ws + FREQ_BYTES);           // 32 KB @ 26 MB
    _Float16* W2t   = (_Float16*)((char*)d_ws + FREQ_BYTES + 65536);   // 32 KB
    _Float16* Atile = (_Float16*)((char*)d_ws + ATILE_OFF);            // 64 MB @ 32 MB
    _Float16* xtab  = (_Float16*)((char*)d_ws + XTAB_OFF);             // 12.8 MB @ 96 MB
    float* out      = (float*)d_out;
    float* out_agg  = out + COORD_ELEMS;

    IRFAggregator_39049842655549_kernel<<<(int)((COORD_ELEMS + 255) / 256), 256, 0, stream>>>(edges, out);
    irfa49s_wgen<<<(128 * KDIM + 255) / 256, 256, 0, stream>>>(Wt);
    irfa49v_w2gen<<<(128 * 128 + 255) / 256, 256, 0, stream>>>(W2t);
    irfa49v_xgen<<<N_NODES / 2, 256, 0, stream>>>(params, xtab);
    irfa49v_spec<<<SPEC_GRID, 256, 0, stream>>>(xtab, W2t, freqh);
    irfa49t_prod<<<(N_ROWS * 32) / 256, 256, 0, stream>>>(freqh, edges, Atile);
    irfa49u_gemm<<<GEMM_GRID, 256, 0, stream>>>(Atile, Wt, out_agg);
}

// Round 23
// 120.036 us; speedup vs baseline: 1.1606x; 1.1606x over previous
//
#include <hip/hip_runtime.h>
#include <hip/hip_bf16.h>

#define N_NODES 50000
#define P_PATHS 200000
#define N_ROWS  250000
#define L_EDGES 6
#define T_LEN   128
#define F_BINS  65
#define EPSF    1e-12f
#define PIF     3.14159265358979323846f
#define COORD_ELEMS ((size_t)2 * (P_PATHS + N_NODES))   // 500000 f32
#define FREQ_BYTES  ((size_t)N_NODES * F_BINS * 8)      // 26 MB mark
#define ATILE_OFF   ((size_t)32 * 1024 * 1024)          // A-tile at +32 MB (64 MB)
#define XTAB_OFF    ((size_t)96 * 1024 * 1024)          // x samples at +96 MB (12.8 MB)
#define PCON_OFF    ((size_t)112 * 1024 * 1024)         // per-node consts at +112 MB
#define KDIM  128
#define KPADN 128
#define ROWS_BLK 64
#define TILES ((N_ROWS + ROWS_BLK - 1) / ROWS_BLK)      // 3907
#define GEMM_GRID 1024
#define STILES ((N_NODES + ROWS_BLK - 1) / ROWS_BLK)    // 782
#define SPEC_GRID 391

typedef _Float16 v2h __attribute__((ext_vector_type(2)));
typedef _Float16 v8h __attribute__((ext_vector_type(8)));
typedef float    v4f __attribute__((ext_vector_type(4)));

__device__ __forceinline__ float softplus_(float x) {
    const float e = __expf(-fabsf(x));
    return fmaxf(x, 0.0f) + __logf(1.0f + e);
}

__device__ __forceinline__ float lgamma_pos_(float x) {
    const float ser = 1.000000000190015f
                    + 76.18009172947146f     / (x + 1.0f)
                    - 86.50532032941677f     / (x + 2.0f)
                    + 24.01409824083091f     / (x + 3.0f)
                    - 1.231739572450155f     / (x + 4.0f)
                    + 0.1208650973866179e-2f / (x + 5.0f)
                    - 0.5395239384953e-5f    / (x + 6.0f);
    const float tmp = x + 5.5f;
    return (x + 0.5f) * __logf(tmp) - tmp + __logf(2.5066282746310005f * ser / x);
}

// ---------------- K0a: irfft weight matrix W^T[t][kk] (unchanged) ----------------
__global__ void irfa49s_wgen(_Float16* __restrict__ Wt) {
    const int idx = blockIdx.x * 256 + threadIdx.x;
    if (idx >= 128 * KDIM) return;
    const int t  = idx / KDIM;
    const int kk = idx - t * KDIM;
    int j; float cj; bool is_sin;
    if (kk == 1) { j = 64; cj = 1.0f; is_sin = false; }
    else {
        j = kk >> 1;
        cj = (j == 0) ? 1.0f : 2.0f;
        is_sin = (kk & 1);
    }
    const int m = (j * t) & 127;
    const float th = (float)m * (PIF / 64.0f);
    const float tri = is_sin ? -__sinf(th) : __cosf(th);
    Wt[idx] = (_Float16)(cj * tri * (1.0f / 128.0f));
}

// ---------------- K0b: forward-rfft weight matrix W2T[kk][t] (unchanged) ----------------
__global__ void irfa49v_w2gen(_Float16* __restrict__ W2t) {
    const int idx = blockIdx.x * 256 + threadIdx.x;
    if (idx >= 128 * 128) return;
    const int kk = idx >> 7;
    const int t  = idx & 127;
    int j; bool is_sin;
    if (kk == 1) { j = 64; is_sin = false; }
    else { j = kk >> 1; is_sin = (kk & 1); }
    const int m = (j * t) & 127;
    const float th = (float)m * (PIF / 64.0f);
    W2t[idx] = (_Float16)(is_sin ? -__sinf(th) : __cosf(th));
}

// ---------------- K1a0: per-node constants (softplus/lgamma ONCE per node) ----------------
__global__ __launch_bounds__(256) void irfa49w_pcon(const float* __restrict__ params,
                                                    float4* __restrict__ pcons) {
    const int n = blockIdx.x * 256 + threadIdx.x;
    if (n >= N_NODES) return;
    const float a  = softplus_(params[2 * n + 0]) + 1.0f;
    const float b  = softplus_(params[2 * n + 1]) + 0.5f;
    const float lg = lgamma_pos_(a);
    const float lb = __logf(b);
    float4 pc;
    pc.x = a - 1.0f;          // am1
    pc.y = 1.0f / b;          // rb
    pc.z = -lg - a * lb;      // cst
    pc.w = 0.0f;
    pcons[n] = pc;
}

// ---------------- K1a: gamma IRF samples -> fp16 xtab[node][128] (light) ----------------
__global__ __launch_bounds__(256) void irfa49w_xgen(const float4* __restrict__ pcons,
                                                    _Float16* __restrict__ xtab) {
    const int tid  = threadIdx.x;
    const int node = blockIdx.x * 2 + (tid >> 7);
    const int t    = tid & 127;
    const float4 pc = pcons[node];        // broadcast, L1-hit
    const float tc = (float)t + 0.5f;
    const float x  = __expf(fmaf(pc.x, __logf(tc), fmaf(-tc, pc.y, pc.z)));
    xtab[(size_t)node * T_LEN + t] = (_Float16)x;
}

// ---------------- K1b: spectrum GEMM F[50000][128] = xtab x W2T^T (unchanged) ----------------
__global__ __launch_bounds__(256, 2) void irfa49v_spec(const _Float16* __restrict__ xtab,
                                                       const _Float16* __restrict__ W2t,
                                                       _Float16* __restrict__ freqh) {
    const int tid  = threadIdx.x;
    const int wv   = tid >> 6;
    const int lane = tid & 63;
    const int tcol = lane & 15;
    const int kg   = lane >> 4;
    const int rgrp = kg * 4;

    v8h bf[4][8];
    #pragma unroll
    for (int kt = 0; kt < 4; ++kt) {
        #pragma unroll
        for (int nt = 0; nt < 8; ++nt) {
            bf[kt][nt] = *(const v8h*)&W2t[(nt * 16 + tcol) * 128 + kt * 32 + kg * 8];
        }
    }

    for (int tile = blockIdx.x; tile < STILES; tile += SPEC_GRID) {
        const int rowa = tile * ROWS_BLK + wv * 16 + tcol;
        v8h af[4];
        #pragma unroll
        for (int kt = 0; kt < 4; ++kt) {
            v8h v = (v8h){(_Float16)0.0f, (_Float16)0.0f, (_Float16)0.0f, (_Float16)0.0f,
                          (_Float16)0.0f, (_Float16)0.0f, (_Float16)0.0f, (_Float16)0.0f};
            if (rowa < N_NODES) v = *(const v8h*)&xtab[(size_t)rowa * T_LEN + kt * 32 + kg * 8];
            af[kt] = v;
        }

        v4f acc[8];
        #pragma unroll
        for (int nt = 0; nt < 8; ++nt) acc[nt] = (v4f){0.0f, 0.0f, 0.0f, 0.0f};
        #pragma unroll
        for (int kt = 0; kt < 4; ++kt) {
            #pragma unroll
            for (int nt = 0; nt < 8; ++nt) {
                acc[nt] = __builtin_amdgcn_mfma_f32_16x16x32_f16(af[kt], bf[kt][nt], acc[nt], 0, 0, 0);
            }
        }

        #pragma unroll
        for (int reg = 0; reg < 4; ++reg) {
            const int row = tile * ROWS_BLK + wv * 16 + rgrp + reg;
            if (row < N_NODES) {
                _Float16* op = freqh + (size_t)row * KPADN;
                #pragma unroll
                for (int nt = 0; nt < 8; ++nt) {
                    op[nt * 16 + tcol] = (_Float16)acc[nt][reg];
                }
            }
        }
    }
}

// ---------------- K2a: spectral product -> packed A-tile (unchanged) ----------------
__global__ __launch_bounds__(256) void irfa49t_prod(const _Float16* __restrict__ freqh,
                                                    const int* __restrict__ edges,
                                                    _Float16* __restrict__ Atile) {
    const int gt  = blockIdx.x * 256 + threadIdx.x;
    const int row = gt >> 5;
    const int tl  = gt & 31;
    _Float16* op = Atile + (size_t)row * KDIM;

    if (row < P_PATHS) {
        const int eb = row * L_EDGES;
        v2h av[L_EDGES], bv[L_EDGES];
        #pragma unroll
        for (int j = 0; j < L_EDGES; ++j) {
            const _Float16* fh = freqh + (size_t)edges[eb + j] * KPADN;
            av[j] = *(const v2h*)(fh + 2 * tl);
            bv[j] = *(const v2h*)(fh + 64 + 2 * tl);
        }
        float p1r = 1.0f, p1i = 0.0f, p2r = 1.0f, p2i = 0.0f, q = 1.0f;
        #pragma unroll
        for (int j = 0; j < L_EDGES; ++j) {
            const float ax  = (float)av[j][0];
            const float ayr = (float)av[j][1];
            const float ay  = (tl == 0) ? 0.0f : ayr;    // bin0.im slot holds f64.re
            float t1 = p1r * ax - p1i * ay;
            p1i      = p1r * ay + p1i * ax;
            p1r = t1;
            q *= ayr;
            const float bx = (float)bv[j][0], by = (float)bv[j][1];
            float t2 = p2r * bx - p2i * by;
            p2i      = p2r * by + p2i * bx;
            p2r = t2;
        }
        v2h h;
        h[0] = (_Float16)p1r;
        h[1] = (tl == 0) ? (_Float16)q : (_Float16)p1i;
        *(v2h*)(op + 2 * tl) = h;
        h[0] = (_Float16)p2r; h[1] = (_Float16)p2i;
        *(v2h*)(op + 64 + 2 * tl) = h;
    } else {
        const _Float16* fh = freqh + (size_t)(row - P_PATHS) * KPADN;
        *(v2h*)(op + 2 * tl)      = *(const v2h*)(fh + 2 * tl);
        *(v2h*)(op + 64 + 2 * tl) = *(const v2h*)(fh + 64 + 2 * tl);
    }
}

// ---------------- K2b: persistent MFMA GEMM, B-in-registers (unchanged) ----------------
__global__ __launch_bounds__(256, 2) void irfa49u_gemm(const _Float16* __restrict__ Atile,
                                                       const _Float16* __restrict__ Wt,
                                                       float* __restrict__ out_agg) {
    const int tid  = threadIdx.x;
    const int wv   = tid >> 6;
    const int lane = tid & 63;
    const int tcol = lane & 15;
    const int kg   = lane >> 4;
    const int rgrp = kg * 4;

    v8h bf[4][8];
    #pragma unroll
    for (int kt = 0; kt < 4; ++kt) {
        #pragma unroll
        for (int nt = 0; nt < 8; ++nt) {
            bf[kt][nt] = *(const v8h*)&Wt[(nt * 16 + tcol) * KDIM + kt * 32 + kg * 8];
        }
    }

    for (int tile = blockIdx.x; tile < TILES; tile += GEMM_GRID) {
        const int rowa = tile * ROWS_BLK + wv * 16 + tcol;
        const _Float16* ap = Atile + (size_t)rowa * KDIM + kg * 8;

        v8h af[4];
        #pragma unroll
        for (int kt = 0; kt < 4; ++kt) af[kt] = *(const v8h*)(ap + kt * 32);

        v4f acc[8];
        #pragma unroll
        for (int nt = 0; nt < 8; ++nt) acc[nt] = (v4f){0.0f, 0.0f, 0.0f, 0.0f};

        #pragma unroll
        for (int kt = 0; kt < 4; ++kt) {
            #pragma unroll
            for (int nt = 0; nt < 8; ++nt) {
                acc[nt] = __builtin_amdgcn_mfma_f32_16x16x32_f16(af[kt], bf[kt][nt], acc[nt], 0, 0, 0);
            }
        }

        #pragma unroll
        for (int reg = 0; reg < 4; ++reg) {
            float vals[8];
            float vsum = 0.0f;
            #pragma unroll
            for (int nt = 0; nt < 8; ++nt) {
                const float v = fmaxf(acc[nt][reg], 0.0f);
                vals[nt] = v;
                vsum += v;
            }
            vsum += __shfl_xor(vsum, 1);
            vsum += __shfl_xor(vsum, 2);
            vsum += __shfl_xor(vsum, 4);
            vsum += __shfl_xor(vsum, 8);
            const int row = tile * ROWS_BLK + wv * 16 + rgrp + reg;
            if (row < N_ROWS) {
                const float inv = 1.0f / (vsum + EPSF);
                float* op = out_agg + (size_t)row * T_LEN;
                #pragma unroll
                for (int nt = 0; nt < 8; ++nt) {
                    const int t = nt * 16 + tcol;
                    op[127 - t] = vals[nt] * inv;
                }
            }
        }
    }
}

// ---------------- K3: coords as f32 (unchanged) ----------------
__global__ void IRFAggregator_39049842655549_kernel(const int* __restrict__ edges,
                                                    float* __restrict__ out) {
    const int M = P_PATHS + N_NODES;
    const int i = blockIdx.x * blockDim.x + threadIdx.x;
    if (i >= 2 * M) return;
    int v;
    if (i < P_PATHS) {
        v = edges[i * L_EDGES];
    } else if (i < M) {
        v = i - P_PATHS;
    } else {
        const int j = i - M;
        if (j < P_PATHS) v = edges[j * L_EDGES + L_EDGES - 1];
        else             v = j - P_PATHS;
    }
    out[i] = (float)v;
}

extern "C" void kernel_launch(void* const* d_in, const int* in_sizes, int n_in,
                              void* d_out, int out_size, void* d_ws, size_t ws_size,
                              hipStream_t stream) {
    const float* params = (const float*)d_in[0];
    const int*   edges  = (const int*)d_in[1];

    _Float16* freqh = (_Float16*)d_ws;                                 // 12.8 MB
    _Float16* Wt    = (_Float16*)((char*)d_ws + FREQ_BYTES);           // 32 KB @ 26 MB
    _Float16* W2t   = (_Float16*)((char*)d_ws + FREQ_BYTES + 65536);   // 32 KB
    _Float16* Atile = (_Float16*)((char*)d_ws + ATILE_OFF);            // 64 MB @ 32 MB
    _Float16* xtab  = (_Float16*)((char*)d_ws + XTAB_OFF);             // 12.8 MB @ 96 MB
    float4*   pcons = (float4*)((char*)d_ws + PCON_OFF);               // 800 KB @ 112 MB
    float* out      = (float*)d_out;
    float* out_agg  = out + COORD_ELEMS;

    IRFAggregator_39049842655549_kernel<<<(int)((COORD_ELEMS + 255) / 256), 256, 0, stream>>>(edges, out);
    irfa49s_wgen<<<(128 * KDIM + 255) / 256, 256, 0, stream>>>(Wt);
    irfa49v_w2gen<<<(128 * 128 + 255) / 256, 256, 0, stream>>>(W2t);
    irfa49w_pcon<<<(N_NODES + 255) / 256, 256, 0, stream>>>(params, pcons);
    irfa49w_xgen<<<N_NODES / 2, 256, 0, stream>>>(pcons, xtab);
    irfa49v_spec<<<SPEC_GRID, 256, 0, stream>>>(xtab, W2t, freqh);
    irfa49t_prod<<<(N_ROWS * 32) / 256, 256, 0, stream>>>(freqh, edges, Atile);
    irfa49u_gemm<<<GEMM_GRID, 256, 0, stream>>>(Atile, Wt, out_agg);
}